// Round 2
// baseline (246.125 us; speedup 1.0000x reference)
//
#include <hip/hip_runtime.h>
#include <hip/hip_bf16.h>

typedef __attribute__((ext_vector_type(8))) short short8;
typedef __attribute__((ext_vector_type(4))) float f32x4;
typedef __attribute__((ext_vector_type(16))) float f32x16;
typedef __attribute__((ext_vector_type(8))) int int8v;

#define D   512
#define NQ  2048
#define NS  4096
#define NB  8
#define BM  128
#define BN  128
#define BK  32

typedef const __attribute__((address_space(1))) unsigned int gas_uint;
typedef __attribute__((address_space(3))) unsigned int las_uint;

// s_waitcnt immediates (gfx9): vmcnt[3:0]|[15:14], expcnt[6:4]=7, lgkmcnt[11:8]=15 = no-wait
#define WAIT_VM4   0x0F74   // vmcnt(4)
#define WAIT_VM2   0x0F72   // vmcnt(2)
#define WAIT_VM0   0x0F70   // vmcnt(0)
#define WAIT_LGKM0 0xC07F   // lgkmcnt(0), vmcnt no-wait

// round-to-nearest-even fp32 -> bf16 bits (fallback path)
__device__ __forceinline__ short f2bf(float f) {
  unsigned u = __builtin_bit_cast(unsigned, f);
  unsigned r = u + 0x7fffu + ((u >> 16) & 1u);
  return (short)(r >> 16);
}

__device__ __forceinline__ short8 pack8(float4 a, float4 b, float r) {
  short8 o;
  o[0] = f2bf(a.x * r); o[1] = f2bf(a.y * r); o[2] = f2bf(a.z * r); o[3] = f2bf(a.w * r);
  o[4] = f2bf(b.x * r); o[5] = f2bf(b.y * r); o[6] = f2bf(b.z * r); o[7] = f2bf(b.w * r);
  return o;
}

// ============================ FAST PATH (fp8 MX) ============================
__global__ void normcvt8_kernel(const float* __restrict__ q, const float* __restrict__ s,
                                unsigned char* __restrict__ qn, unsigned char* __restrict__ sn,
                                unsigned* __restrict__ maxenc) {
  if (blockIdx.x < 64) maxenc[(blockIdx.x << 8) | threadIdx.x] = 0;
  int wave = blockIdx.x * 4 + (threadIdx.x >> 6);
  int lane = threadIdx.x & 63;
  const int NQR = NB * NQ;
  const float4* src; unsigned char* dst;
  if (wave < NQR) { src = (const float4*)(q + (size_t)wave * D); dst = qn + (size_t)wave * D; }
  else {
    size_t w = wave - NQR;
    src = (const float4*)(s + w * D); dst = sn + w * D;
  }
  float4 a = src[lane * 2];
  float4 b = src[lane * 2 + 1];
  float ss = a.x*a.x + a.y*a.y + a.z*a.z + a.w*a.w
           + b.x*b.x + b.y*b.y + b.z*b.z + b.w*b.w;
  #pragma unroll
  for (int m = 32; m >= 1; m >>= 1) ss += __shfl_xor(ss, m, 64);
  float r = 1.0f / fmaxf(sqrtf(ss), 1e-12f);
  int w0 = __builtin_amdgcn_cvt_pk_fp8_f32(a.x * r, a.y * r, 0, false);
  w0     = __builtin_amdgcn_cvt_pk_fp8_f32(a.z * r, a.w * r, w0, true);
  int w1 = __builtin_amdgcn_cvt_pk_fp8_f32(b.x * r, b.y * r, 0, false);
  w1     = __builtin_amdgcn_cvt_pk_fp8_f32(b.z * r, b.w * r, w1, true);
  *(int2*)(dst + lane * 8) = make_int2(w0, w1);
}

// ---------------------------------------------------------------------------
// cosmax12: round-11 pipeline (4x16KB buffers, prefetch distance 3, raw
// s_barrier, XCD-aware decode) retiled from M=64/256thr to M=128/512thr:
//  - 8 waves (4 m-strips x 2 n-halves), per-wave body IDENTICAL to round 11
//    (4 MFMA + 8 ds_read_b128 per phase, ~124 VGPR) -> 16 waves/CU.
//  - each 16KB S-buffer (128 s-rows x 128B K-quarter) now feeds 128 q-rows:
//    phases per block 64 -> 32, S-stage DMA per block halves (1024 s-rows).
//  - Q region = 128 rows x 512B = 64KB, shares sbuf with the 4 stage
//    buffers: staged, A-frags read to regs, then recycled. Buffer prefetch
//    starts after the A-frag barrier (one extra DMA-latency stall, once).
//  - issue() = 2 global_load_lds per thread (512 thr x 2 x 16B = 16KB), so
//    steady-state wait is vmcnt(4) (3 buffers x 2 in flight, drain oldest 2).
// ---------------------------------------------------------------------------
__global__ __launch_bounds__(512, 4) void cosmax12_kernel(
    const unsigned char* __restrict__ Qn, const unsigned char* __restrict__ Sn,
    unsigned int* __restrict__ maxenc)
{
  __shared__ __align__(16) unsigned char sbuf[65536];   // 4 x 16 KB stage buffers / Q
  __shared__ float maxbuf[128][2];

  const int id  = blockIdx.x;          // 512 blocks, 1-D
  const int b   = id & 7;              // XCD-aligned batch (round-robin id->XCD)
  const int j   = id >> 3;             // 0..63
  const int mt  = j & 15;              // 128-row q tile
  const int nsp = j >> 4;              // 0..3 : 1024-row s quarter
  const int tid  = threadIdx.x;
  const int wave = tid >> 6;           // 0..7
  const int lane = tid & 63;
  const int l31 = lane & 31, kc = lane >> 5;
  const int mstrip = wave & 3, nhalf = wave >> 2;

  // ---------------- Q prologue: stage 128x512B into sbuf[0..65536) ----------
  {
    const unsigned char* Qbase = Qn + ((size_t)b * NQ + (size_t)mt * 128) * D;
    const int baserow = wave * 2 + (lane >> 5);          // 0..15
    #pragma unroll
    for (int p = 0; p < 8; ++p) {
      int row = p * 16 + baserow;                         // 0..127
      int g   = (lane & 31) ^ (row & 31);                 // 16B-chunk XOR swizzle
      __builtin_amdgcn_global_load_lds(
          (gas_uint*)(Qbase + (size_t)row * D + g * 16),
          (las_uint*)(sbuf + p * 8192 + wave * 1024), 16, 0, 0);
    }
  }
  __syncthreads();                                        // drains Q DMA

  // ---------------- S staging setup (per-lane global base) ------------------
  const int srow8 = lane >> 3;                            // 0..7
  const int sch   = (lane & 7) ^ srow8;
  const unsigned char* gS = Sn +
      ((size_t)b * NS + (size_t)nsp * 1024 + wave * 16 + srow8) * D + sch * 16;

  auto issue = [&](size_t goff, int ldsoff) {
    #pragma unroll
    for (int t = 0; t < 2; ++t)
      __builtin_amdgcn_global_load_lds((gas_uint*)(gS + goff + (size_t)t * 4096),
          (las_uint*)(sbuf + ldsoff + wave * 2048 + t * 1024), 16, 0, 0);
  };

  // ---------------- A fragments: registers, full K ---------------------------
  const int arow = mstrip * 32 + l31;
  int8v a[8];
  #pragma unroll
  for (int kk = 0; kk < 8; ++kk) {
    int c0 = (4 * kk + 2 * kc) ^ l31;
    ((int4*)&a[kk])[0] = *(const int4*)&sbuf[arow * 512 + c0 * 16];
    ((int4*)&a[kk])[1] = *(const int4*)&sbuf[arow * 512 + (c0 ^ 1) * 16];
  }
  // all waves must finish reading Q before stage DMA overwrites sbuf
  __builtin_amdgcn_s_waitcnt(WAIT_LGKM0);
  asm volatile("" ::: "memory");
  __builtin_amdgcn_s_barrier();
  asm volatile("" ::: "memory");
  issue(0,   0);                                          // (tile0,kt0) -> buf0
  issue(128, 16384);                                      // (tile0,kt1) -> buf1
  issue(256, 32768);                                      // (tile0,kt2) -> buf2

  // ---------------- accumulators --------------------------------------------
  const int brow0 = (nhalf * 64 + l31) * 128;
  const int brow1 = brow0 + 4096;                         // +32 s-rows
  const int cxor  = ((kc * 2) ^ (l31 & 7)) * 16;

  f32x16 acc0, acc1;
  float rmax[16];
  #pragma unroll
  for (int r = 0; r < 16; ++r) rmax[r] = -2.0f;

  auto computeK = [&](int kt, int rdo) {
    const unsigned char* Bb = sbuf + rdo;
    #pragma unroll
    for (int ss = 0; ss < 2; ++ss) {
      const int cb = cxor ^ (ss * 64);
      int8v b0, b1;
      ((int4*)&b0)[0] = *(const int4*)&Bb[brow0 + cb];
      ((int4*)&b0)[1] = *(const int4*)&Bb[brow0 + (cb ^ 16)];
      ((int4*)&b1)[0] = *(const int4*)&Bb[brow1 + cb];
      ((int4*)&b1)[1] = *(const int4*)&Bb[brow1 + (cb ^ 16)];
      acc0 = __builtin_amdgcn_mfma_scale_f32_32x32x64_f8f6f4(
          a[kt * 2 + ss], b0, acc0, 0, 0, 0, 0x7f7f7f7f, 0, 0x7f7f7f7f);
      acc1 = __builtin_amdgcn_mfma_scale_f32_32x32x64_f8f6f4(
          a[kt * 2 + ss], b1, acc1, 0, 0, 0, 0x7f7f7f7f, 0, 0x7f7f7f7f);
    }
  };

  #pragma clang loop unroll(disable)
  for (int nt2 = 0; nt2 < 8; ++nt2) {
    const size_t ntb = (size_t)nt2 << 16;                 // 128 rows * 512 B
    const bool more = (nt2 < 7);

    // ---- kt = 0 : read buf0, issue (tile,kt3) -> buf3
    __builtin_amdgcn_s_waitcnt(WAIT_VM4);
    asm volatile("" ::: "memory");
    __builtin_amdgcn_s_barrier();
    asm volatile("" ::: "memory");
    issue(ntb + 384, 49152);
    #pragma unroll
    for (int r = 0; r < 16; ++r) { acc0[r] = 0.f; acc1[r] = 0.f; }
    computeK(0, 0);

    // ---- kt = 1 : read buf1, issue (tile+1,kt0) -> buf0
    __builtin_amdgcn_s_waitcnt(WAIT_VM4);
    asm volatile("" ::: "memory");
    __builtin_amdgcn_s_barrier();
    asm volatile("" ::: "memory");
    if (more) issue(ntb + 65536, 0);
    computeK(1, 16384);

    // ---- kt = 2 : read buf2, issue (tile+1,kt1) -> buf1
    if (more) __builtin_amdgcn_s_waitcnt(WAIT_VM4);
    else      __builtin_amdgcn_s_waitcnt(WAIT_VM2);
    asm volatile("" ::: "memory");
    __builtin_amdgcn_s_barrier();
    asm volatile("" ::: "memory");
    if (more) issue(ntb + 65536 + 128, 16384);
    computeK(2, 32768);

    // ---- kt = 3 : read buf3, issue (tile+1,kt2) -> buf2
    if (more) __builtin_amdgcn_s_waitcnt(WAIT_VM4);
    else      __builtin_amdgcn_s_waitcnt(WAIT_VM0);
    asm volatile("" ::: "memory");
    __builtin_amdgcn_s_barrier();
    asm volatile("" ::: "memory");
    if (more) issue(ntb + 65536 + 256, 32768);
    computeK(3, 49152);

    #pragma unroll
    for (int r = 0; r < 16; ++r)
      rmax[r] = fmaxf(rmax[r], fmaxf(acc0[r], acc1[r]));
  }

  // ---------------- epilogue -------------------------------------------------
  // 32x32 C/D: col = lane&31, row = (reg&3) + 8*(reg>>2) + 4*(lane>>5)
  #pragma unroll
  for (int r = 0; r < 16; ++r) {
    float v = rmax[r];
    v = fmaxf(v, __shfl_xor(v, 1, 64));
    v = fmaxf(v, __shfl_xor(v, 2, 64));
    v = fmaxf(v, __shfl_xor(v, 4, 64));
    v = fmaxf(v, __shfl_xor(v, 8, 64));
    v = fmaxf(v, __shfl_xor(v, 16, 64));
    if (l31 == 0)
      maxbuf[mstrip * 32 + (r & 3) + 8 * (r >> 2) + 4 * kc][nhalf] = v;
  }
  __syncthreads();

  if (tid < 128) {
    float v = fmaxf(maxbuf[tid][0], maxbuf[tid][1]);
    unsigned e = __builtin_bit_cast(unsigned, v);
    e = ((int)e >= 0) ? (e | 0x80000000u) : ~e;           // monotone float->uint
    atomicMax(&maxenc[(size_t)b * NQ + (size_t)mt * 128 + tid], e);
  }
}

__global__ void finalize_kernel(const unsigned* __restrict__ maxenc,
                                float* __restrict__ out) {
  int b = blockIdx.x;
  int tid = threadIdx.x;
  float sum = 0.f;
  for (int i = tid; i < NQ; i += 256) {
    unsigned e = maxenc[(size_t)b * NQ + i];
    unsigned u = (e & 0x80000000u) ? (e & 0x7fffffffu) : ~e;
    float v = __builtin_bit_cast(float, u);
    sum += 1.0f - v;
  }
  #pragma unroll
  for (int m = 32; m >= 1; m >>= 1) sum += __shfl_xor(sum, m, 64);
  __shared__ float part[4];
  if ((tid & 63) == 0) part[tid >> 6] = sum;
  __syncthreads();
  if (tid == 0) out[b] = (part[0] + part[1] + part[2] + part[3]) * (1.0f / (float)NQ);
}

// ====================== FALLBACK PATH (round-1, proven, tiny ws) ============
__global__ void norms_kernel(const float* __restrict__ q, const float* __restrict__ s,
                             float* __restrict__ rq, float* __restrict__ rs) {
  int wave = blockIdx.x * 4 + (threadIdx.x >> 6);
  int lane = threadIdx.x & 63;
  const int NQR = NB * NQ, NSR = NB * NS;
  if (wave >= NQR + NSR) return;
  const float4* r4; float* outp;
  if (wave < NQR) { r4 = (const float4*)(q + (size_t)wave * D); outp = rq + wave; }
  else           { r4 = (const float4*)(s + (size_t)(wave - NQR) * D); outp = rs + (wave - NQR); }
  float4 a = r4[lane];
  float4 b = r4[lane + 64];
  float ss = a.x*a.x + a.y*a.y + a.z*a.z + a.w*a.w
           + b.x*b.x + b.y*b.y + b.z*b.z + b.w*b.w;
  #pragma unroll
  for (int m = 32; m >= 1; m >>= 1) ss += __shfl_xor(ss, m, 64);
  if (lane == 0) *outp = 1.0f / fmaxf(sqrtf(ss), 1e-12f);
}

__global__ __launch_bounds__(256, 3) void cosmax_kernel(
    const float* __restrict__ Q, const float* __restrict__ S,
    const float* __restrict__ rq, const float* __restrict__ rs,
    unsigned int* __restrict__ maxenc)
{
  __shared__ short As[BM * BK];
  __shared__ short Bs[BN * BK];
  __shared__ float maxbuf[BM][2];

  const int b  = blockIdx.z, mt = blockIdx.y, nt = blockIdx.x;
  const float* Qb  = Q + ((size_t)b * NQ + mt * BM) * D;
  const float* Sb  = S + ((size_t)b * NS + nt * BN) * D;
  const float* rqb = rq + (size_t)b * NQ + mt * BM;
  const float* rsb = rs + (size_t)b * NS + nt * BN;

  const int tid  = threadIdx.x;
  const int srow = tid >> 2;
  const int kseg = (tid & 3) * 8;
  const float rq0 = rqb[srow], rq1 = rqb[srow + 64];
  const float rs0 = rsb[srow], rs1 = rsb[srow + 64];
  const int wave = tid >> 6, lane = tid & 63;
  const int wm = (wave & 1) * 64, wn = (wave >> 1) * 64;
  const int lm = lane & 15, lk = (lane >> 4) * 8;

  f32x4 acc[4][4];
  #pragma unroll
  for (int i = 0; i < 4; ++i)
    #pragma unroll
    for (int j = 0; j < 4; ++j) acc[i][j] = (f32x4){0.f, 0.f, 0.f, 0.f};

  const float* qrow0 = Qb + (size_t)srow * D + kseg;
  const float* qrow1 = qrow0 + (size_t)64 * D;
  const float* srow0 = Sb + (size_t)srow * D + kseg;
  const float* srow1 = srow0 + (size_t)64 * D;

  float4 qa, qb2, qc, qd, sa, sb2, sc, sd;
  #define LOADK(k0)                                                    \
    qa  = *(const float4*)(qrow0 + (k0));  qb2 = *(const float4*)(qrow0 + (k0) + 4); \
    qc  = *(const float4*)(qrow1 + (k0));  qd  = *(const float4*)(qrow1 + (k0) + 4); \
    sa  = *(const float4*)(srow0 + (k0));  sb2 = *(const float4*)(srow0 + (k0) + 4); \
    sc  = *(const float4*)(srow1 + (k0));  sd  = *(const float4*)(srow1 + (k0) + 4);
  LOADK(0);
  #pragma unroll 4
  for (int kt = 0; kt < D / BK; ++kt) {
    *(short8*)&As[srow        * BK + kseg] = pack8(qa, qb2, rq0);
    *(short8*)&As[(srow + 64) * BK + kseg] = pack8(qc, qd,  rq1);
    *(short8*)&Bs[srow        * BK + kseg] = pack8(sa, sb2, rs0);
    *(short8*)&Bs[(srow + 64) * BK + kseg] = pack8(sc, sd,  rs1);
    __syncthreads();
    if (kt < D / BK - 1) { LOADK((kt + 1) * BK); }
    short8 af[4], bf[4];
    #pragma unroll
    for (int i = 0; i < 4; ++i) af[i] = *(short8*)&As[(wm + i * 16 + lm) * BK + lk];
    #pragma unroll
    for (int j = 0; j < 4; ++j) bf[j] = *(short8*)&Bs[(wn + j * 16 + lm) * BK + lk];
    #pragma unroll
    for (int i = 0; i < 4; ++i)
      #pragma unroll
      for (int j = 0; j < 4; ++j)
        acc[i][j] = __builtin_amdgcn_mfma_f32_16x16x32_bf16(af[i], bf[j], acc[i][j], 0, 0, 0);
    __syncthreads();
  }
  #undef LOADK

  #pragma unroll
  for (int i = 0; i < 4; ++i) {
    #pragma unroll
    for (int r = 0; r < 4; ++r) {
      float v = fmaxf(fmaxf(acc[i][0][r], acc[i][1][r]),
                      fmaxf(acc[i][2][r], acc[i][3][r]));
      v = fmaxf(v, __shfl_xor(v, 1, 64));
      v = fmaxf(v, __shfl_xor(v, 2, 64));
      v = fmaxf(v, __shfl_xor(v, 4, 64));
      v = fmaxf(v, __shfl_xor(v, 8, 64));
      if ((lane & 15) == 0) {
        int row = wm + i * 16 + (lane >> 4) * 4 + r;
        maxbuf[row][wave >> 1] = v;
      }
    }
  }
  __syncthreads();
  if (tid < BM) {
    float v = fmaxf(maxbuf[tid][0], maxbuf[tid][1]);
    unsigned e = __builtin_bit_cast(unsigned, v);
    e = ((int)e >= 0) ? (e | 0x80000000u) : ~e;
    atomicMax(&maxenc[(size_t)b * NQ + mt * BM + tid], e);
  }
}

// ============================================================================
extern "C" void kernel_launch(void* const* d_in, const int* in_sizes, int n_in,
                              void* d_out, int out_size, void* d_ws, size_t ws_size,
                              hipStream_t stream) {
  const float* q = (const float*)d_in[0];   // [8,2048,512]
  const float* s = (const float*)d_in[1];   // [8,4096,512]
  float* out = (float*)d_out;               // [8]

  unsigned* maxenc = (unsigned*)d_ws;                         // 64 KB
  const size_t QOFF = 65536;
  const size_t SOFF = QOFF + (size_t)NB * NQ * D;             // +8 MiB (fp8)
  const size_t NEED = SOFF + (size_t)NB * NS * D;             // +16 MiB (~25.2 MB total)

  if (ws_size >= NEED) {
    unsigned char* qn = (unsigned char*)d_ws + QOFF;
    unsigned char* sn = (unsigned char*)d_ws + SOFF;
    normcvt8_kernel<<<NB * (NQ + NS) / 4, 256, 0, stream>>>(q, s, qn, sn, maxenc);
    cosmax12_kernel<<<512, 512, 0, stream>>>(qn, sn, maxenc);   // M=128, 8 waves
    finalize_kernel<<<NB, 256, 0, stream>>>(maxenc, out);
  } else {
    float* rq = (float*)((char*)d_ws + 65536);
    float* rs = (float*)((char*)d_ws + 131072);
    hipMemsetAsync(maxenc, 0, (size_t)NB * NQ * sizeof(unsigned), stream);
    norms_kernel<<<NB * (NQ + NS) / 4, 256, 0, stream>>>(q, s, rq, rs);
    dim3 grid(NS / BN, NQ / BM, NB);
    cosmax_kernel<<<grid, 256, 0, stream>>>(q, s, rq, rs, maxenc);
    finalize_kernel<<<NB, 256, 0, stream>>>(maxenc, out);
  }
}

// Round 3
// 184.885 us; speedup vs baseline: 1.3312x; 1.3312x over previous
//
#include <hip/hip_runtime.h>
#include <hip/hip_bf16.h>

typedef __attribute__((ext_vector_type(8))) short short8;
typedef __attribute__((ext_vector_type(4))) float f32x4;
typedef __attribute__((ext_vector_type(16))) float f32x16;
typedef __attribute__((ext_vector_type(8))) int int8v;

#define D   512
#define NQ  2048
#define NS  4096
#define NB  8
#define BM  128
#define BN  128
#define BK  32

typedef const __attribute__((address_space(1))) unsigned int gas_uint;
typedef __attribute__((address_space(3))) unsigned int las_uint;

// s_waitcnt immediates (gfx9): vmcnt[3:0]|[15:14], expcnt[6:4]=7, lgkmcnt[11:8]=15 = no-wait
#define WAIT_VM8   0x0F78   // vmcnt(8)
#define WAIT_VM4   0x0F74   // vmcnt(4)
#define WAIT_VM0   0x0F70   // vmcnt(0)
#define WAIT_LGKM0 0xC07F   // lgkmcnt(0), vmcnt no-wait

// round-to-nearest-even fp32 -> bf16 bits (fallback path)
__device__ __forceinline__ short f2bf(float f) {
  unsigned u = __builtin_bit_cast(unsigned, f);
  unsigned r = u + 0x7fffu + ((u >> 16) & 1u);
  return (short)(r >> 16);
}

__device__ __forceinline__ short8 pack8(float4 a, float4 b, float r) {
  short8 o;
  o[0] = f2bf(a.x * r); o[1] = f2bf(a.y * r); o[2] = f2bf(a.z * r); o[3] = f2bf(a.w * r);
  o[4] = f2bf(b.x * r); o[5] = f2bf(b.y * r); o[6] = f2bf(b.z * r); o[7] = f2bf(b.w * r);
  return o;
}

// ============================ FAST PATH (fp8 MX) ============================
__global__ void normcvt8_kernel(const float* __restrict__ q, const float* __restrict__ s,
                                unsigned char* __restrict__ qn, unsigned char* __restrict__ sn,
                                unsigned* __restrict__ maxenc) {
  if (blockIdx.x < 64) maxenc[(blockIdx.x << 8) | threadIdx.x] = 0;
  int wave = blockIdx.x * 4 + (threadIdx.x >> 6);
  int lane = threadIdx.x & 63;
  const int NQR = NB * NQ;
  const float4* src; unsigned char* dst;
  if (wave < NQR) { src = (const float4*)(q + (size_t)wave * D); dst = qn + (size_t)wave * D; }
  else {
    size_t w = wave - NQR;
    src = (const float4*)(s + w * D); dst = sn + w * D;
  }
  float4 a = src[lane * 2];
  float4 b = src[lane * 2 + 1];
  float ss = a.x*a.x + a.y*a.y + a.z*a.z + a.w*a.w
           + b.x*b.x + b.y*b.y + b.z*b.z + b.w*b.w;
  #pragma unroll
  for (int m = 32; m >= 1; m >>= 1) ss += __shfl_xor(ss, m, 64);
  float r = 1.0f / fmaxf(sqrtf(ss), 1e-12f);
  int w0 = __builtin_amdgcn_cvt_pk_fp8_f32(a.x * r, a.y * r, 0, false);
  w0     = __builtin_amdgcn_cvt_pk_fp8_f32(a.z * r, a.w * r, w0, true);
  int w1 = __builtin_amdgcn_cvt_pk_fp8_f32(b.x * r, b.y * r, 0, false);
  w1     = __builtin_amdgcn_cvt_pk_fp8_f32(b.z * r, b.w * r, w1, true);
  *(int2*)(dst + lane * 8) = make_int2(w0, w1);
}

// ---------------------------------------------------------------------------
// cosmax13: round-11 pipeline (256 thr, 4x16KB buffers, prefetch distance 3,
// vmcnt(8) steady, raw s_barrier, XCD-aware decode) with doubled MFMA density:
//  - each wave holds TWO persistent A strips (a[2][8], 64 q-rows, 128 VGPR)
//    and reuses each B fragment for both -> 8 MFMA per 8 ds_read_b128 per
//    phase (was 4:8). Per-CU phase: MFMA ~1100 cyc > LDS ~1024 cyc ->
//    matrix-pipe becomes the floor (round-1 was LDS+barrier bound at 1700).
//  - block tile M=128 (4 waves = 2 m-strips x 2 n-halves): per (b,mt) pair
//    4 blocks cover NS in quarters -> 32 phases/block (was 64), half the
//    barrier joins.
//  - Q region = 128 rows x 512B = 64KB = the whole buffer region; staged,
//    A-frags read to regs, then the 4 stage buffers recycle it. The 3
//    initial S issues happen after the A-read barrier (one-time DMA bubble).
//  - __launch_bounds__(256, 2): under BOTH "blocks/CU" (CUDA) and "waves/EU"
//    readings this yields a 256-VGPR budget. Round-2 proved (512,4) means
//    4 blocks/CU -> 64 VGPR -> total spill; do not touch.
// ---------------------------------------------------------------------------
__global__ __launch_bounds__(256, 2) void cosmax13_kernel(
    const unsigned char* __restrict__ Qn, const unsigned char* __restrict__ Sn,
    unsigned int* __restrict__ maxenc)
{
  __shared__ __align__(16) unsigned char sbuf[65536];   // 4 x 16 KB stage buffers / Q
  __shared__ float maxbuf[128][2];

  const int id  = blockIdx.x;          // 512 blocks, 1-D
  const int b   = id & 7;              // XCD-aligned batch (round-robin id->XCD)
  const int j   = id >> 3;             // 0..63
  const int mt  = j & 15;              // 128-row q tile
  const int nsp = j >> 4;              // 0..3 : 1024-row s quarter
  const int tid  = threadIdx.x;
  const int wave = tid >> 6;           // 0..3
  const int lane = tid & 63;
  const int l31 = lane & 31, kc = lane >> 5;
  const int mstrip = wave & 1, nhalf = wave >> 1;

  // ---------------- Q prologue: stage 128x512B into sbuf[0..65536) ----------
  {
    const unsigned char* Qbase = Qn + ((size_t)b * NQ + (size_t)mt * 128) * D;
    const int baserow = wave * 2 + (lane >> 5);          // 0..7
    #pragma unroll
    for (int p = 0; p < 16; ++p) {
      int row = p * 8 + baserow;                          // 0..127
      int g   = (lane & 31) ^ (row & 31);                 // 16B-chunk XOR swizzle
      __builtin_amdgcn_global_load_lds(
          (gas_uint*)(Qbase + (size_t)row * D + g * 16),
          (las_uint*)(sbuf + p * 4096 + wave * 1024), 16, 0, 0);
    }
  }
  __syncthreads();                                        // drains Q DMA

  // ---------------- S staging setup (per-lane global base) ------------------
  const int srow8 = lane >> 3;                            // 0..7
  const int sch   = (lane & 7) ^ srow8;
  const unsigned char* gS = Sn +
      ((size_t)b * NS + (size_t)nsp * 1024 + wave * 32 + srow8) * D + sch * 16;

  auto issue = [&](size_t goff, int ldsoff) {
    #pragma unroll
    for (int t = 0; t < 4; ++t)
      __builtin_amdgcn_global_load_lds((gas_uint*)(gS + goff + (size_t)t * 4096),
          (las_uint*)(sbuf + ldsoff + wave * 4096 + t * 1024), 16, 0, 0);
  };

  // ---------------- A fragments: registers, 64 q-rows, full K ---------------
  // rows mstrip*64 + m*32 + l31 ; physical chunk = logical ^ (row&31)
  int8v a[2][8];
  #pragma unroll
  for (int m = 0; m < 2; ++m) {
    const int arow = mstrip * 64 + m * 32 + l31;
    #pragma unroll
    for (int kk = 0; kk < 8; ++kk) {
      int c0 = (4 * kk + 2 * kc) ^ l31;
      ((int4*)&a[m][kk])[0] = *(const int4*)&sbuf[arow * 512 + c0 * 16];
      ((int4*)&a[m][kk])[1] = *(const int4*)&sbuf[arow * 512 + (c0 ^ 1) * 16];
    }
  }
  // all waves must finish reading Q before stage DMA overwrites sbuf
  __builtin_amdgcn_s_waitcnt(WAIT_LGKM0);
  asm volatile("" ::: "memory");
  __builtin_amdgcn_s_barrier();
  asm volatile("" ::: "memory");
  issue(0,   0);                                          // (tile0,kt0) -> buf0
  issue(128, 16384);                                      // (tile0,kt1) -> buf1
  issue(256, 32768);                                      // (tile0,kt2) -> buf2

  // ---------------- accumulators --------------------------------------------
  const int brow0 = (nhalf * 64 + l31) * 128;
  const int brow1 = brow0 + 4096;                         // +32 s-rows
  const int cxor  = ((kc * 2) ^ (l31 & 7)) * 16;

  f32x16 acc00, acc01, acc10, acc11;
  float rmax0[16], rmax1[16];
  #pragma unroll
  for (int r = 0; r < 16; ++r) { rmax0[r] = -2.0f; rmax1[r] = -2.0f; }

  auto computeK = [&](int kt, int rdo) {
    const unsigned char* Bb = sbuf + rdo;
    #pragma unroll
    for (int ss = 0; ss < 2; ++ss) {
      const int cb = cxor ^ (ss * 64);
      int8v b0, b1;
      ((int4*)&b0)[0] = *(const int4*)&Bb[brow0 + cb];
      ((int4*)&b0)[1] = *(const int4*)&Bb[brow0 + (cb ^ 16)];
      acc00 = __builtin_amdgcn_mfma_scale_f32_32x32x64_f8f6f4(
          a[0][kt * 2 + ss], b0, acc00, 0, 0, 0, 0x7f7f7f7f, 0, 0x7f7f7f7f);
      acc10 = __builtin_amdgcn_mfma_scale_f32_32x32x64_f8f6f4(
          a[1][kt * 2 + ss], b0, acc10, 0, 0, 0, 0x7f7f7f7f, 0, 0x7f7f7f7f);
      ((int4*)&b1)[0] = *(const int4*)&Bb[brow1 + cb];
      ((int4*)&b1)[1] = *(const int4*)&Bb[brow1 + (cb ^ 16)];
      acc01 = __builtin_amdgcn_mfma_scale_f32_32x32x64_f8f6f4(
          a[0][kt * 2 + ss], b1, acc01, 0, 0, 0, 0x7f7f7f7f, 0, 0x7f7f7f7f);
      acc11 = __builtin_amdgcn_mfma_scale_f32_32x32x64_f8f6f4(
          a[1][kt * 2 + ss], b1, acc11, 0, 0, 0, 0x7f7f7f7f, 0, 0x7f7f7f7f);
    }
  };

  #pragma clang loop unroll(disable)
  for (int nt2 = 0; nt2 < 8; ++nt2) {
    const size_t ntb = (size_t)nt2 << 16;                 // 128 rows * 512 B
    const bool more = (nt2 < 7);

    // ---- kt = 0 : read buf0, issue (tile,kt3) -> buf3
    __builtin_amdgcn_s_waitcnt(WAIT_VM8);
    asm volatile("" ::: "memory");
    __builtin_amdgcn_s_barrier();
    asm volatile("" ::: "memory");
    issue(ntb + 384, 49152);
    #pragma unroll
    for (int r = 0; r < 16; ++r) { acc00[r] = 0.f; acc01[r] = 0.f; acc10[r] = 0.f; acc11[r] = 0.f; }
    computeK(0, 0);

    // ---- kt = 1 : read buf1, issue (tile+1,kt0) -> buf0
    __builtin_amdgcn_s_waitcnt(WAIT_VM8);
    asm volatile("" ::: "memory");
    __builtin_amdgcn_s_barrier();
    asm volatile("" ::: "memory");
    if (more) issue(ntb + 65536, 0);
    computeK(1, 16384);

    // ---- kt = 2 : read buf2, issue (tile+1,kt1) -> buf1
    if (more) __builtin_amdgcn_s_waitcnt(WAIT_VM8);
    else      __builtin_amdgcn_s_waitcnt(WAIT_VM4);
    asm volatile("" ::: "memory");
    __builtin_amdgcn_s_barrier();
    asm volatile("" ::: "memory");
    if (more) issue(ntb + 65536 + 128, 16384);
    computeK(2, 32768);

    // ---- kt = 3 : read buf3, issue (tile+1,kt2) -> buf2
    if (more) __builtin_amdgcn_s_waitcnt(WAIT_VM8);
    else      __builtin_amdgcn_s_waitcnt(WAIT_VM0);
    asm volatile("" ::: "memory");
    __builtin_amdgcn_s_barrier();
    asm volatile("" ::: "memory");
    if (more) issue(ntb + 65536 + 256, 32768);
    computeK(3, 49152);

    #pragma unroll
    for (int r = 0; r < 16; ++r) {
      rmax0[r] = fmaxf(rmax0[r], fmaxf(acc00[r], acc01[r]));
      rmax1[r] = fmaxf(rmax1[r], fmaxf(acc10[r], acc11[r]));
    }
  }

  // ---------------- epilogue -------------------------------------------------
  // 32x32 C/D: col = lane&31, row = (reg&3) + 8*(reg>>2) + 4*(lane>>5)
  #pragma unroll
  for (int m = 0; m < 2; ++m) {
    #pragma unroll
    for (int r = 0; r < 16; ++r) {
      float v = m ? rmax1[r] : rmax0[r];
      v = fmaxf(v, __shfl_xor(v, 1, 64));
      v = fmaxf(v, __shfl_xor(v, 2, 64));
      v = fmaxf(v, __shfl_xor(v, 4, 64));
      v = fmaxf(v, __shfl_xor(v, 8, 64));
      v = fmaxf(v, __shfl_xor(v, 16, 64));
      if (l31 == 0)
        maxbuf[mstrip * 64 + m * 32 + (r & 3) + 8 * (r >> 2) + 4 * kc][nhalf] = v;
    }
  }
  __syncthreads();

  if (tid < 128) {
    float v = fmaxf(maxbuf[tid][0], maxbuf[tid][1]);
    unsigned e = __builtin_bit_cast(unsigned, v);
    e = ((int)e >= 0) ? (e | 0x80000000u) : ~e;           // monotone float->uint
    atomicMax(&maxenc[(size_t)b * NQ + (size_t)mt * 128 + tid], e);
  }
}

__global__ void finalize_kernel(const unsigned* __restrict__ maxenc,
                                float* __restrict__ out) {
  int b = blockIdx.x;
  int tid = threadIdx.x;
  float sum = 0.f;
  for (int i = tid; i < NQ; i += 256) {
    unsigned e = maxenc[(size_t)b * NQ + i];
    unsigned u = (e & 0x80000000u) ? (e & 0x7fffffffu) : ~e;
    float v = __builtin_bit_cast(float, u);
    sum += 1.0f - v;
  }
  #pragma unroll
  for (int m = 32; m >= 1; m >>= 1) sum += __shfl_xor(sum, m, 64);
  __shared__ float part[4];
  if ((tid & 63) == 0) part[tid >> 6] = sum;
  __syncthreads();
  if (tid == 0) out[b] = (part[0] + part[1] + part[2] + part[3]) * (1.0f / (float)NQ);
}

// ====================== FALLBACK PATH (round-1, proven, tiny ws) ============
__global__ void norms_kernel(const float* __restrict__ q, const float* __restrict__ s,
                             float* __restrict__ rq, float* __restrict__ rs) {
  int wave = blockIdx.x * 4 + (threadIdx.x >> 6);
  int lane = threadIdx.x & 63;
  const int NQR = NB * NQ, NSR = NB * NS;
  if (wave >= NQR + NSR) return;
  const float4* r4; float* outp;
  if (wave < NQR) { r4 = (const float4*)(q + (size_t)wave * D); outp = rq + wave; }
  else           { r4 = (const float4*)(s + (size_t)(wave - NQR) * D); outp = rs + (wave - NQR); }
  float4 a = r4[lane];
  float4 b = r4[lane + 64];
  float ss = a.x*a.x + a.y*a.y + a.z*a.z + a.w*a.w
           + b.x*b.x + b.y*b.y + b.z*b.z + b.w*b.w;
  #pragma unroll
  for (int m = 32; m >= 1; m >>= 1) ss += __shfl_xor(ss, m, 64);
  if (lane == 0) *outp = 1.0f / fmaxf(sqrtf(ss), 1e-12f);
}

__global__ __launch_bounds__(256, 3) void cosmax_kernel(
    const float* __restrict__ Q, const float* __restrict__ S,
    const float* __restrict__ rq, const float* __restrict__ rs,
    unsigned int* __restrict__ maxenc)
{
  __shared__ short As[BM * BK];
  __shared__ short Bs[BN * BK];
  __shared__ float maxbuf[BM][2];

  const int b  = blockIdx.z, mt = blockIdx.y, nt = blockIdx.x;
  const float* Qb  = Q + ((size_t)b * NQ + mt * BM) * D;
  const float* Sb  = S + ((size_t)b * NS + nt * BN) * D;
  const float* rqb = rq + (size_t)b * NQ + mt * BM;
  const float* rsb = rs + (size_t)b * NS + nt * BN;

  const int tid  = threadIdx.x;
  const int srow = tid >> 2;
  const int kseg = (tid & 3) * 8;
  const float rq0 = rqb[srow], rq1 = rqb[srow + 64];
  const float rs0 = rsb[srow], rs1 = rsb[srow + 64];
  const int wave = tid >> 6, lane = tid & 63;
  const int wm = (wave & 1) * 64, wn = (wave >> 1) * 64;
  const int lm = lane & 15, lk = (lane >> 4) * 8;

  f32x4 acc[4][4];
  #pragma unroll
  for (int i = 0; i < 4; ++i)
    #pragma unroll
    for (int j = 0; j < 4; ++j) acc[i][j] = (f32x4){0.f, 0.f, 0.f, 0.f};

  const float* qrow0 = Qb + (size_t)srow * D + kseg;
  const float* qrow1 = qrow0 + (size_t)64 * D;
  const float* srow0 = Sb + (size_t)srow * D + kseg;
  const float* srow1 = srow0 + (size_t)64 * D;

  float4 qa, qb2, qc, qd, sa, sb2, sc, sd;
  #define LOADK(k0)                                                    \
    qa  = *(const float4*)(qrow0 + (k0));  qb2 = *(const float4*)(qrow0 + (k0) + 4); \
    qc  = *(const float4*)(qrow1 + (k0));  qd  = *(const float4*)(qrow1 + (k0) + 4); \
    sa  = *(const float4*)(srow0 + (k0));  sb2 = *(const float4*)(srow0 + (k0) + 4); \
    sc  = *(const float4*)(srow1 + (k0));  sd  = *(const float4*)(srow1 + (k0) + 4);
  LOADK(0);
  #pragma unroll 4
  for (int kt = 0; kt < D / BK; ++kt) {
    *(short8*)&As[srow        * BK + kseg] = pack8(qa, qb2, rq0);
    *(short8*)&As[(srow + 64) * BK + kseg] = pack8(qc, qd,  rq1);
    *(short8*)&Bs[srow        * BK + kseg] = pack8(sa, sb2, rs0);
    *(short8*)&Bs[(srow + 64) * BK + kseg] = pack8(sc, sd,  rs1);
    __syncthreads();
    if (kt < D / BK - 1) { LOADK((kt + 1) * BK); }
    short8 af[4], bf[4];
    #pragma unroll
    for (int i = 0; i < 4; ++i) af[i] = *(short8*)&As[(wm + i * 16 + lm) * BK + lk];
    #pragma unroll
    for (int j = 0; j < 4; ++j) bf[j] = *(short8*)&Bs[(wn + j * 16 + lm) * BK + lk];
    #pragma unroll
    for (int i = 0; i < 4; ++i)
      #pragma unroll
      for (int j = 0; j < 4; ++j)
        acc[i][j] = __builtin_amdgcn_mfma_f32_16x16x32_bf16(af[i], bf[j], acc[i][j], 0, 0, 0);
    __syncthreads();
  }
  #undef LOADK

  #pragma unroll
  for (int i = 0; i < 4; ++i) {
    #pragma unroll
    for (int r = 0; r < 4; ++r) {
      float v = fmaxf(fmaxf(acc[i][0][r], acc[i][1][r]),
                      fmaxf(acc[i][2][r], acc[i][3][r]));
      v = fmaxf(v, __shfl_xor(v, 1, 64));
      v = fmaxf(v, __shfl_xor(v, 2, 64));
      v = fmaxf(v, __shfl_xor(v, 4, 64));
      v = fmaxf(v, __shfl_xor(v, 8, 64));
      if ((lane & 15) == 0) {
        int row = wm + i * 16 + (lane >> 4) * 4 + r;
        maxbuf[row][wave >> 1] = v;
      }
    }
  }
  __syncthreads();
  if (tid < BM) {
    float v = fmaxf(maxbuf[tid][0], maxbuf[tid][1]);
    unsigned e = __builtin_bit_cast(unsigned, v);
    e = ((int)e >= 0) ? (e | 0x80000000u) : ~e;
    atomicMax(&maxenc[(size_t)b * NQ + mt * BM + tid], e);
  }
}

// ============================================================================
extern "C" void kernel_launch(void* const* d_in, const int* in_sizes, int n_in,
                              void* d_out, int out_size, void* d_ws, size_t ws_size,
                              hipStream_t stream) {
  const float* q = (const float*)d_in[0];   // [8,2048,512]
  const float* s = (const float*)d_in[1];   // [8,4096,512]
  float* out = (float*)d_out;               // [8]

  unsigned* maxenc = (unsigned*)d_ws;                         // 64 KB
  const size_t QOFF = 65536;
  const size_t SOFF = QOFF + (size_t)NB * NQ * D;             // +8 MiB (fp8)
  const size_t NEED = SOFF + (size_t)NB * NS * D;             // +16 MiB (~25.2 MB total)

  if (ws_size >= NEED) {
    unsigned char* qn = (unsigned char*)d_ws + QOFF;
    unsigned char* sn = (unsigned char*)d_ws + SOFF;
    normcvt8_kernel<<<NB * (NQ + NS) / 4, 256, 0, stream>>>(q, s, qn, sn, maxenc);
    cosmax13_kernel<<<512, 256, 0, stream>>>(qn, sn, maxenc);   // M=128, 8:8 MFMA:ds
    finalize_kernel<<<NB, 256, 0, stream>>>(maxenc, out);
  } else {
    float* rq = (float*)((char*)d_ws + 65536);
    float* rs = (float*)((char*)d_ws + 131072);
    hipMemsetAsync(maxenc, 0, (size_t)NB * NQ * sizeof(unsigned), stream);
    norms_kernel<<<NB * (NQ + NS) / 4, 256, 0, stream>>>(q, s, rq, rs);
    dim3 grid(NS / BN, NQ / BM, NB);
    cosmax_kernel<<<grid, 256, 0, stream>>>(q, s, rq, rs, maxenc);
    finalize_kernel<<<NB, 256, 0, stream>>>(maxenc, out);
  }
}

// Round 4
// 167.124 us; speedup vs baseline: 1.4727x; 1.1063x over previous
//
#include <hip/hip_runtime.h>
#include <hip/hip_bf16.h>

typedef __attribute__((ext_vector_type(8))) short short8;
typedef __attribute__((ext_vector_type(4))) float f32x4;
typedef __attribute__((ext_vector_type(16))) float f32x16;
typedef __attribute__((ext_vector_type(8))) int int8v;

#define D   512
#define NQ  2048
#define NS  4096
#define NB  8
#define BM  128
#define BN  128
#define BK  32

typedef const __attribute__((address_space(1))) unsigned int gas_uint;
typedef __attribute__((address_space(3))) unsigned int las_uint;

// s_waitcnt immediates (gfx9): vmcnt[3:0]|[15:14], expcnt[6:4]=7, lgkmcnt[11:8]=15 = no-wait
#define WAIT_VM8   0x0F78   // vmcnt(8)
#define WAIT_VM0   0x0F70   // vmcnt(0)
#define WAIT_LGKM0 0xC07F   // lgkmcnt(0), vmcnt no-wait

// round-to-nearest-even fp32 -> bf16 bits (fallback path)
__device__ __forceinline__ short f2bf(float f) {
  unsigned u = __builtin_bit_cast(unsigned, f);
  unsigned r = u + 0x7fffu + ((u >> 16) & 1u);
  return (short)(r >> 16);
}

__device__ __forceinline__ short8 pack8(float4 a, float4 b, float r) {
  short8 o;
  o[0] = f2bf(a.x * r); o[1] = f2bf(a.y * r); o[2] = f2bf(a.z * r); o[3] = f2bf(a.w * r);
  o[4] = f2bf(b.x * r); o[5] = f2bf(b.y * r); o[6] = f2bf(b.z * r); o[7] = f2bf(b.w * r);
  return o;
}

// ============================ FAST PATH (fp8 MX) ============================
__global__ void normcvt8_kernel(const float* __restrict__ q, const float* __restrict__ s,
                                unsigned char* __restrict__ qn, unsigned char* __restrict__ sn,
                                unsigned* __restrict__ maxenc) {
  if (blockIdx.x < 64) maxenc[(blockIdx.x << 8) | threadIdx.x] = 0;
  int wave = blockIdx.x * 4 + (threadIdx.x >> 6);
  int lane = threadIdx.x & 63;
  const int NQR = NB * NQ;
  const float4* src; unsigned char* dst;
  if (wave < NQR) { src = (const float4*)(q + (size_t)wave * D); dst = qn + (size_t)wave * D; }
  else {
    size_t w = wave - NQR;
    src = (const float4*)(s + w * D); dst = sn + w * D;
  }
  float4 a = src[lane * 2];
  float4 b = src[lane * 2 + 1];
  float ss = a.x*a.x + a.y*a.y + a.z*a.z + a.w*a.w
           + b.x*b.x + b.y*b.y + b.z*b.z + b.w*b.w;
  #pragma unroll
  for (int m = 32; m >= 1; m >>= 1) ss += __shfl_xor(ss, m, 64);
  float r = 1.0f / fmaxf(sqrtf(ss), 1e-12f);
  int w0 = __builtin_amdgcn_cvt_pk_fp8_f32(a.x * r, a.y * r, 0, false);
  w0     = __builtin_amdgcn_cvt_pk_fp8_f32(a.z * r, a.w * r, w0, true);
  int w1 = __builtin_amdgcn_cvt_pk_fp8_f32(b.x * r, b.y * r, 0, false);
  w1     = __builtin_amdgcn_cvt_pk_fp8_f32(b.z * r, b.w * r, w1, true);
  *(int2*)(dst + lane * 8) = make_int2(w0, w1);
}

// ---------------------------------------------------------------------------
// cosmax14: cosmax11 geometry (M=64, 512 blocks = 8b x 32mt x 2nsp, 256 thr,
// 4x16KB buffers, XCD decode) with B-reuse and pair-phases:
//  - waves = 4 N-QUARTERS (32 s-rows each). Every wave holds BOTH 32-row A
//    strips in regs (a[2][8] = 128 VGPR) and reads ONE B fragment per ss ->
//    2 ds_read feed 2 MFMAs (strip0,strip1). LDS floor per CU halves:
//    49K -> 24.5K cyc; matrix pipe (35.2K cyc) becomes the binding pipe.
//  - register bill ~193 arch + 32 acc = ~225 <= 256-budget of (256,2).
//    cosmax13 failed at 268 (a[2][8] + 4 accs) -> allocator split 128/128
//    and spilled (87MB fetch / 34MB write scratch traffic). Two accs only.
//  - pair-phases: one wait+barrier per 2 buffers (32 phases, was 64).
//    Issue into a pair happens at the START of the phase AFTER it was read
//    (post-barrier => race-free, cosmax11 discipline). Flight = 1 full
//    phase (~1600 cyc) covers L2 latency. vm(0) waits drain exactly the
//    pair we need (nothing else outstanding at that point).
// ---------------------------------------------------------------------------
__global__ __launch_bounds__(256, 2) void cosmax14_kernel(
    const unsigned char* __restrict__ Qn, const unsigned char* __restrict__ Sn,
    unsigned int* __restrict__ maxenc)
{
  __shared__ __align__(16) unsigned char sbuf[65536];   // 4 x 16 KB stage buffers
  __shared__ float maxbuf[64][4];

  const int id  = blockIdx.x;          // 512 blocks, 1-D
  const int b   = id & 7;              // XCD-aligned batch (round-robin id->XCD)
  const int j   = id >> 3;             // 0..63
  const int mt  = j & 31;              // 64-row q tile
  const int nsp = j >> 5;              // 0..1 : 2048-row s half
  const int tid  = threadIdx.x;
  const int wave = tid >> 6;           // 0..3 : n-quarter within the 128-row buffer
  const int lane = tid & 63;
  const int l31 = lane & 31, kc = lane >> 5;

  // ---------------- Q prologue: stage 64x512B into sbuf[16384..49152) -------
  {
    const unsigned char* Qbase = Qn + ((size_t)b * NQ + (size_t)mt * 64) * D;
    const int baserow = wave * 2 + (lane >> 5);          // 0..7
    #pragma unroll
    for (int p = 0; p < 8; ++p) {
      int row = p * 8 + baserow;                          // 0..63
      int g   = (lane & 31) ^ (row & 31);                 // 16B-chunk XOR swizzle
      __builtin_amdgcn_global_load_lds(
          (gas_uint*)(Qbase + (size_t)row * D + g * 16),
          (las_uint*)(sbuf + 16384 + p * 4096 + wave * 1024), 16, 0, 0);
    }
  }
  __syncthreads();                                        // drains Q DMA

  // ---------------- S staging setup (per-lane global base) ------------------
  const int srow8 = lane >> 3;                            // 0..7
  const int sch   = (lane & 7) ^ srow8;
  const unsigned char* gS = Sn +
      ((size_t)b * NS + (size_t)nsp * 2048 + wave * 32 + srow8) * D + sch * 16;

  auto issue = [&](size_t goff, int ldsoff) {
    #pragma unroll
    for (int t = 0; t < 4; ++t)
      __builtin_amdgcn_global_load_lds((gas_uint*)(gS + goff + (size_t)t * 4096),
          (las_uint*)(sbuf + ldsoff + wave * 4096 + t * 1024), 16, 0, 0);
  };

  // stage (tile0,kt0) -> buf0 [0,16384): disjoint from Q region; overlaps A reads
  issue(0, 0);

  // ---------------- A fragments: registers, BOTH strips, full K -------------
  int8v a[2][8];
  #pragma unroll
  for (int m = 0; m < 2; ++m) {
    const int arow = m * 32 + l31;
    #pragma unroll
    for (int kk = 0; kk < 8; ++kk) {
      int c0 = (4 * kk + 2 * kc) ^ l31;
      ((int4*)&a[m][kk])[0] = *(const int4*)&sbuf[16384 + arow * 512 + c0 * 16];
      ((int4*)&a[m][kk])[1] = *(const int4*)&sbuf[16384 + arow * 512 + (c0 ^ 1) * 16];
    }
  }
  // all waves must finish reading Q before stage DMA overwrites buf1/buf2/buf3
  __builtin_amdgcn_s_waitcnt(WAIT_LGKM0);
  asm volatile("" ::: "memory");
  __builtin_amdgcn_s_barrier();
  asm volatile("" ::: "memory");
  issue(128, 16384);                                      // (tile0,kt1) -> buf1
  issue(256, 32768);                                      // (tile0,kt2) -> buf2
  issue(384, 49152);                                      // (tile0,kt3) -> buf3

  // ---------------- accumulators --------------------------------------------
  // this wave's 32 s-rows: global s-row = nsp*2048 + nt2*128 + wave*32 + l31
  const int brow = (wave * 32 + l31) * 128;
  const int cxor = ((kc * 2) ^ (l31 & 7)) * 16;

  f32x16 acc0, acc1;                                      // strip0, strip1
  float rmax0[16], rmax1[16];
  #pragma unroll
  for (int r = 0; r < 16; ++r) { rmax0[r] = -2.0f; rmax1[r] = -2.0f; }

  auto computeK = [&](int kt, int rdo) {
    const unsigned char* Bb = sbuf + rdo;
    #pragma unroll
    for (int ss = 0; ss < 2; ++ss) {
      const int cb = cxor ^ (ss * 64);
      int8v b0;
      ((int4*)&b0)[0] = *(const int4*)&Bb[brow + cb];
      ((int4*)&b0)[1] = *(const int4*)&Bb[brow + (cb ^ 16)];
      acc0 = __builtin_amdgcn_mfma_scale_f32_32x32x64_f8f6f4(
          a[0][kt * 2 + ss], b0, acc0, 0, 0, 0, 0x7f7f7f7f, 0, 0x7f7f7f7f);
      acc1 = __builtin_amdgcn_mfma_scale_f32_32x32x64_f8f6f4(
          a[1][kt * 2 + ss], b0, acc1, 0, 0, 0, 0x7f7f7f7f, 0, 0x7f7f7f7f);
    }
  };

  #pragma clang loop unroll(disable)
  for (int nt2 = 0; nt2 < 16; ++nt2) {
    const size_t ntb = (size_t)nt2 << 16;                 // 128 rows * 512 B
    const bool more = (nt2 < 15);

    // ---- phase A : compute bufs {0,1}; issue next-tile pair {2,3} ----------
    if (nt2 == 0) __builtin_amdgcn_s_waitcnt(WAIT_VM8);   // bufs 2,3 still flying
    else          __builtin_amdgcn_s_waitcnt(WAIT_VM0);   // drain P0(nt2)
    asm volatile("" ::: "memory");
    __builtin_amdgcn_s_barrier();
    asm volatile("" ::: "memory");
    if (nt2 > 0) {                                        // bufs 2,3 were read last phase
      issue(ntb + 256, 32768);                            // (tile,kt2) -> buf2
      issue(ntb + 384, 49152);                            // (tile,kt3) -> buf3
    }
    #pragma unroll
    for (int r = 0; r < 16; ++r) { acc0[r] = 0.f; acc1[r] = 0.f; }
    computeK(0, 0);
    computeK(1, 16384);

    // ---- phase B : compute bufs {2,3}; issue next-tile pair {0,1} ----------
    __builtin_amdgcn_s_waitcnt(WAIT_VM0);                 // drain P1(nt2)
    asm volatile("" ::: "memory");
    __builtin_amdgcn_s_barrier();
    asm volatile("" ::: "memory");
    if (more) {                                           // bufs 0,1 were read last phase
      issue(ntb + 65536, 0);                              // (tile+1,kt0) -> buf0
      issue(ntb + 65536 + 128, 16384);                    // (tile+1,kt1) -> buf1
    }
    computeK(2, 32768);
    computeK(3, 49152);

    #pragma unroll
    for (int r = 0; r < 16; ++r) {
      rmax0[r] = fmaxf(rmax0[r], acc0[r]);
      rmax1[r] = fmaxf(rmax1[r], acc1[r]);
    }
  }

  // ---------------- epilogue -------------------------------------------------
  // 32x32 C/D: col = lane&31 (s-row in quarter), row = (reg&3)+8*(reg>>2)+4*(lane>>5)
  #pragma unroll
  for (int m = 0; m < 2; ++m) {
    #pragma unroll
    for (int r = 0; r < 16; ++r) {
      float v = m ? rmax1[r] : rmax0[r];
      v = fmaxf(v, __shfl_xor(v, 1, 64));
      v = fmaxf(v, __shfl_xor(v, 2, 64));
      v = fmaxf(v, __shfl_xor(v, 4, 64));
      v = fmaxf(v, __shfl_xor(v, 8, 64));
      v = fmaxf(v, __shfl_xor(v, 16, 64));
      if (l31 == 0)
        maxbuf[m * 32 + (r & 3) + 8 * (r >> 2) + 4 * kc][wave] = v;
    }
  }
  __syncthreads();

  if (tid < 64) {
    float v = fmaxf(fmaxf(maxbuf[tid][0], maxbuf[tid][1]),
                    fmaxf(maxbuf[tid][2], maxbuf[tid][3]));
    unsigned e = __builtin_bit_cast(unsigned, v);
    e = ((int)e >= 0) ? (e | 0x80000000u) : ~e;           // monotone float->uint
    atomicMax(&maxenc[(size_t)b * NQ + (size_t)mt * 64 + tid], e);
  }
}

__global__ void finalize_kernel(const unsigned* __restrict__ maxenc,
                                float* __restrict__ out) {
  int b = blockIdx.x;
  int tid = threadIdx.x;
  float sum = 0.f;
  for (int i = tid; i < NQ; i += 256) {
    unsigned e = maxenc[(size_t)b * NQ + i];
    unsigned u = (e & 0x80000000u) ? (e & 0x7fffffffu) : ~e;
    float v = __builtin_bit_cast(float, u);
    sum += 1.0f - v;
  }
  #pragma unroll
  for (int m = 32; m >= 1; m >>= 1) sum += __shfl_xor(sum, m, 64);
  __shared__ float part[4];
  if ((tid & 63) == 0) part[tid >> 6] = sum;
  __syncthreads();
  if (tid == 0) out[b] = (part[0] + part[1] + part[2] + part[3]) * (1.0f / (float)NQ);
}

// ====================== FALLBACK PATH (round-1, proven, tiny ws) ============
__global__ void norms_kernel(const float* __restrict__ q, const float* __restrict__ s,
                             float* __restrict__ rq, float* __restrict__ rs) {
  int wave = blockIdx.x * 4 + (threadIdx.x >> 6);
  int lane = threadIdx.x & 63;
  const int NQR = NB * NQ, NSR = NB * NS;
  if (wave >= NQR + NSR) return;
  const float4* r4; float* outp;
  if (wave < NQR) { r4 = (const float4*)(q + (size_t)wave * D); outp = rq + wave; }
  else           { r4 = (const float4*)(s + (size_t)(wave - NQR) * D); outp = rs + (wave - NQR); }
  float4 a = r4[lane];
  float4 b = r4[lane + 64];
  float ss = a.x*a.x + a.y*a.y + a.z*a.z + a.w*a.w
           + b.x*b.x + b.y*b.y + b.z*b.z + b.w*b.w;
  #pragma unroll
  for (int m = 32; m >= 1; m >>= 1) ss += __shfl_xor(ss, m, 64);
  if (lane == 0) *outp = 1.0f / fmaxf(sqrtf(ss), 1e-12f);
}

__global__ __launch_bounds__(256, 3) void cosmax_kernel(
    const float* __restrict__ Q, const float* __restrict__ S,
    const float* __restrict__ rq, const float* __restrict__ rs,
    unsigned int* __restrict__ maxenc)
{
  __shared__ short As[BM * BK];
  __shared__ short Bs[BN * BK];
  __shared__ float maxbuf[BM][2];

  const int b  = blockIdx.z, mt = blockIdx.y, nt = blockIdx.x;
  const float* Qb  = Q + ((size_t)b * NQ + mt * BM) * D;
  const float* Sb  = S + ((size_t)b * NS + nt * BN) * D;
  const float* rqb = rq + (size_t)b * NQ + mt * BM;
  const float* rsb = rs + (size_t)b * NS + nt * BN;

  const int tid  = threadIdx.x;
  const int srow = tid >> 2;
  const int kseg = (tid & 3) * 8;
  const float rq0 = rqb[srow], rq1 = rqb[srow + 64];
  const float rs0 = rsb[srow], rs1 = rsb[srow + 64];
  const int wave = tid >> 6, lane = tid & 63;
  const int wm = (wave & 1) * 64, wn = (wave >> 1) * 64;
  const int lm = lane & 15, lk = (lane >> 4) * 8;

  f32x4 acc[4][4];
  #pragma unroll
  for (int i = 0; i < 4; ++i)
    #pragma unroll
    for (int j = 0; j < 4; ++j) acc[i][j] = (f32x4){0.f, 0.f, 0.f, 0.f};

  const float* qrow0 = Qb + (size_t)srow * D + kseg;
  const float* qrow1 = qrow0 + (size_t)64 * D;
  const float* srow0 = Sb + (size_t)srow * D + kseg;
  const float* srow1 = srow0 + (size_t)64 * D;

  float4 qa, qb2, qc, qd, sa, sb2, sc, sd;
  #define LOADK(k0)                                                    \
    qa  = *(const float4*)(qrow0 + (k0));  qb2 = *(const float4*)(qrow0 + (k0) + 4); \
    qc  = *(const float4*)(qrow1 + (k0));  qd  = *(const float4*)(qrow1 + (k0) + 4); \
    sa  = *(const float4*)(srow0 + (k0));  sb2 = *(const float4*)(srow0 + (k0) + 4); \
    sc  = *(const float4*)(srow1 + (k0));  sd  = *(const float4*)(srow1 + (k0) + 4);
  LOADK(0);
  #pragma unroll 4
  for (int kt = 0; kt < D / BK; ++kt) {
    *(short8*)&As[srow        * BK + kseg] = pack8(qa, qb2, rq0);
    *(short8*)&As[(srow + 64) * BK + kseg] = pack8(qc, qd,  rq1);
    *(short8*)&Bs[srow        * BK + kseg] = pack8(sa, sb2, rs0);
    *(short8*)&Bs[(srow + 64) * BK + kseg] = pack8(sc, sd,  rs1);
    __syncthreads();
    if (kt < D / BK - 1) { LOADK((kt + 1) * BK); }
    short8 af[4], bf[4];
    #pragma unroll
    for (int i = 0; i < 4; ++i) af[i] = *(short8*)&As[(wm + i * 16 + lm) * BK + lk];
    #pragma unroll
    for (int j = 0; j < 4; ++j) bf[j] = *(short8*)&Bs[(wn + j * 16 + lm) * BK + lk];
    #pragma unroll
    for (int i = 0; i < 4; ++i)
      #pragma unroll
      for (int j = 0; j < 4; ++j)
        acc[i][j] = __builtin_amdgcn_mfma_f32_16x16x32_bf16(af[i], bf[j], acc[i][j], 0, 0, 0);
    __syncthreads();
  }
  #undef LOADK

  #pragma unroll
  for (int i = 0; i < 4; ++i) {
    #pragma unroll
    for (int r = 0; r < 4; ++r) {
      float v = fmaxf(fmaxf(acc[i][0][r], acc[i][1][r]),
                      fmaxf(acc[i][2][r], acc[i][3][r]));
      v = fmaxf(v, __shfl_xor(v, 1, 64));
      v = fmaxf(v, __shfl_xor(v, 2, 64));
      v = fmaxf(v, __shfl_xor(v, 4, 64));
      v = fmaxf(v, __shfl_xor(v, 8, 64));
      if ((lane & 15) == 0) {
        int row = wm + i * 16 + (lane >> 4) * 4 + r;
        maxbuf[row][wave >> 1] = v;
      }
    }
  }
  __syncthreads();
  if (tid < BM) {
    float v = fmaxf(maxbuf[tid][0], maxbuf[tid][1]);
    unsigned e = __builtin_bit_cast(unsigned, v);
    e = ((int)e >= 0) ? (e | 0x80000000u) : ~e;
    atomicMax(&maxenc[(size_t)b * NQ + mt * BM + tid], e);
  }
}

// ============================================================================
extern "C" void kernel_launch(void* const* d_in, const int* in_sizes, int n_in,
                              void* d_out, int out_size, void* d_ws, size_t ws_size,
                              hipStream_t stream) {
  const float* q = (const float*)d_in[0];   // [8,2048,512]
  const float* s = (const float*)d_in[1];   // [8,4096,512]
  float* out = (float*)d_out;               // [8]

  unsigned* maxenc = (unsigned*)d_ws;                         // 64 KB
  const size_t QOFF = 65536;
  const size_t SOFF = QOFF + (size_t)NB * NQ * D;             // +8 MiB (fp8)
  const size_t NEED = SOFF + (size_t)NB * NS * D;             // +16 MiB (~25.2 MB total)

  if (ws_size >= NEED) {
    unsigned char* qn = (unsigned char*)d_ws + QOFF;
    unsigned char* sn = (unsigned char*)d_ws + SOFF;
    normcvt8_kernel<<<NB * (NQ + NS) / 4, 256, 0, stream>>>(q, s, qn, sn, maxenc);
    cosmax14_kernel<<<512, 256, 0, stream>>>(qn, sn, maxenc);   // B-reuse, pair-phases
    finalize_kernel<<<NB, 256, 0, stream>>>(maxenc, out);
  } else {
    float* rq = (float*)((char*)d_ws + 65536);
    float* rs = (float*)((char*)d_ws + 131072);
    hipMemsetAsync(maxenc, 0, (size_t)NB * NQ * sizeof(unsigned), stream);
    norms_kernel<<<NB * (NQ + NS) / 4, 256, 0, stream>>>(q, s, rq, rs);
    dim3 grid(NS / BN, NQ / BM, NB);
    cosmax_kernel<<<grid, 256, 0, stream>>>(q, s, rq, rs, maxenc);
    finalize_kernel<<<NB, 256, 0, stream>>>(maxenc, out);
  }
}

// Round 5
// 159.646 us; speedup vs baseline: 1.5417x; 1.0468x over previous
//
#include <hip/hip_runtime.h>
#include <hip/hip_bf16.h>

typedef __attribute__((ext_vector_type(8))) short short8;
typedef __attribute__((ext_vector_type(4))) float f32x4;
typedef __attribute__((ext_vector_type(16))) float f32x16;
typedef __attribute__((ext_vector_type(8))) int int8v;

#define D   512
#define NQ  2048
#define NS  4096
#define NB  8
#define BM  128
#define BN  128
#define BK  32

typedef const __attribute__((address_space(1))) unsigned int gas_uint;
typedef __attribute__((address_space(3))) unsigned int las_uint;

// s_waitcnt immediates (gfx9): vmcnt[3:0]|[15:14], expcnt[6:4]=7, lgkmcnt[11:8]=15 = no-wait
#define WAIT_VM12  0x0F7C   // vmcnt(12)
#define WAIT_VM8   0x0F78   // vmcnt(8)
#define WAIT_VM4   0x0F74   // vmcnt(4)
#define WAIT_VM0   0x0F70   // vmcnt(0)
#define WAIT_LGKM0 0xC07F   // lgkmcnt(0), vmcnt no-wait

// round-to-nearest-even fp32 -> bf16 bits (fallback path)
__device__ __forceinline__ short f2bf(float f) {
  unsigned u = __builtin_bit_cast(unsigned, f);
  unsigned r = u + 0x7fffu + ((u >> 16) & 1u);
  return (short)(r >> 16);
}

__device__ __forceinline__ short8 pack8(float4 a, float4 b, float r) {
  short8 o;
  o[0] = f2bf(a.x * r); o[1] = f2bf(a.y * r); o[2] = f2bf(a.z * r); o[3] = f2bf(a.w * r);
  o[4] = f2bf(b.x * r); o[5] = f2bf(b.y * r); o[6] = f2bf(b.z * r); o[7] = f2bf(b.w * r);
  return o;
}

// ============================ FAST PATH (fp8 MX) ============================
__global__ void normcvt8_kernel(const float* __restrict__ q, const float* __restrict__ s,
                                unsigned char* __restrict__ qn, unsigned char* __restrict__ sn,
                                unsigned* __restrict__ maxenc) {
  if (blockIdx.x < 64) maxenc[(blockIdx.x << 8) | threadIdx.x] = 0;
  int wave = blockIdx.x * 4 + (threadIdx.x >> 6);
  int lane = threadIdx.x & 63;
  const int NQR = NB * NQ;
  const float4* src; unsigned char* dst;
  if (wave < NQR) { src = (const float4*)(q + (size_t)wave * D); dst = qn + (size_t)wave * D; }
  else {
    size_t w = wave - NQR;
    src = (const float4*)(s + w * D); dst = sn + w * D;
  }
  float4 a = src[lane * 2];
  float4 b = src[lane * 2 + 1];
  float ss = a.x*a.x + a.y*a.y + a.z*a.z + a.w*a.w
           + b.x*b.x + b.y*b.y + b.z*b.z + b.w*b.w;
  #pragma unroll
  for (int m = 32; m >= 1; m >>= 1) ss += __shfl_xor(ss, m, 64);
  float r = 1.0f / fmaxf(sqrtf(ss), 1e-12f);
  int w0 = __builtin_amdgcn_cvt_pk_fp8_f32(a.x * r, a.y * r, 0, false);
  w0     = __builtin_amdgcn_cvt_pk_fp8_f32(a.z * r, a.w * r, w0, true);
  int w1 = __builtin_amdgcn_cvt_pk_fp8_f32(b.x * r, b.y * r, 0, false);
  w1     = __builtin_amdgcn_cvt_pk_fp8_f32(b.z * r, b.w * r, w1, true);
  *(int2*)(dst + lane * 8) = make_int2(w0, w1);
}

// ---------------------------------------------------------------------------
// cosmax15: BARRIER-FREE main loop.
// Insight from r4: with waves = n-quarters and A in registers (cosmax14),
// each wave's stage buffers are WAVE-PRIVATE (wave w DMA-writes only the
// wave*4096 quarter of each 16KB buf and ds_reads only rows wave*32..+31).
// The per-phase barrier + collective vmcnt drain was pure inherited
// overhead — and r1/r4 showed two different phase geometries both pinned
// at ~32% MfmaUtil = the barrier-rhythm ceiling, with ~45% of SIMD cycles
// idle at the joins.
// Now each wave free-runs a 64-step stream (16 tiles x 4 kt):
//   issue(step+3) ; s_waitcnt vmcnt(12) ; 4x ds_read_b128 ;
//   setprio(1) ; 4 MFMA ; setprio(0)
//  - counted vmcnt never 0 until tail (12/12/12/... then 8/4/0): step i's
//    4 loads retire when <=12 newer remain. Flight = 3 steps covers L2.
//  - 8 independent wave-streams/CU anti-phase naturally -> latency hiding
//    without any barrier joins. setprio biases MFMA-entering waves (m191
//    regime: desynchronized waves, not m190 lockstep).
//  - single prologue barrier remains: Q staging/A-frag reads ARE cross-wave
//    (Q overlaps bufs 1,2). buf0 issue overlaps A-reads (disjoint region).
//  - registers: a[2][8]=128 + 2 acc + 4 b-frag; (256,2) budget, r4 compiled
//    at VGPR_Count 120 with zero spill. Grid/layout byte-identical to r4.
// ---------------------------------------------------------------------------
__global__ __launch_bounds__(256, 2) void cosmax15_kernel(
    const unsigned char* __restrict__ Qn, const unsigned char* __restrict__ Sn,
    unsigned int* __restrict__ maxenc)
{
  __shared__ __align__(16) unsigned char sbuf[65536];   // 4 x 16 KB stage buffers
  __shared__ float maxbuf[64][4];

  const int id  = blockIdx.x;          // 512 blocks, 1-D
  const int b   = id & 7;              // XCD-aligned batch (round-robin id->XCD)
  const int j   = id >> 3;             // 0..63
  const int mt  = j & 31;              // 64-row q tile
  const int nsp = j >> 5;              // 0..1 : 2048-row s half
  const int tid  = threadIdx.x;
  const int wave = tid >> 6;           // 0..3 : n-quarter (wave-private stream)
  const int lane = tid & 63;
  const int l31 = lane & 31, kc = lane >> 5;

  // ---------------- Q prologue: stage 64x512B into sbuf[16384..49152) -------
  {
    const unsigned char* Qbase = Qn + ((size_t)b * NQ + (size_t)mt * 64) * D;
    const int baserow = wave * 2 + (lane >> 5);          // 0..7
    #pragma unroll
    for (int p = 0; p < 8; ++p) {
      int row = p * 8 + baserow;                          // 0..63
      int g   = (lane & 31) ^ (row & 31);                 // 16B-chunk XOR swizzle
      __builtin_amdgcn_global_load_lds(
          (gas_uint*)(Qbase + (size_t)row * D + g * 16),
          (las_uint*)(sbuf + 16384 + p * 4096 + wave * 1024), 16, 0, 0);
    }
  }
  __syncthreads();                                        // drains Q DMA

  // ---------------- S staging setup (per-lane global base) ------------------
  const int srow8 = lane >> 3;                            // 0..7
  const int sch   = (lane & 7) ^ srow8;
  const unsigned char* gS = Sn +
      ((size_t)b * NS + (size_t)nsp * 2048 + wave * 32 + srow8) * D + sch * 16;

  auto issue = [&](size_t goff, int ldsoff) {
    #pragma unroll
    for (int t = 0; t < 4; ++t)
      __builtin_amdgcn_global_load_lds((gas_uint*)(gS + goff + (size_t)t * 4096),
          (las_uint*)(sbuf + ldsoff + wave * 4096 + t * 1024), 16, 0, 0);
  };

  // stage (tile0,kt0) -> buf0 [0,16384): disjoint from Q region; overlaps A reads
  issue(0, 0);

  // ---------------- A fragments: registers, BOTH strips, full K -------------
  int8v a[2][8];
  #pragma unroll
  for (int m = 0; m < 2; ++m) {
    const int arow = m * 32 + l31;
    #pragma unroll
    for (int kk = 0; kk < 8; ++kk) {
      int c0 = (4 * kk + 2 * kc) ^ l31;
      ((int4*)&a[m][kk])[0] = *(const int4*)&sbuf[16384 + arow * 512 + c0 * 16];
      ((int4*)&a[m][kk])[1] = *(const int4*)&sbuf[16384 + arow * 512 + (c0 ^ 1) * 16];
    }
  }
  // all waves must finish reading Q before stage DMA overwrites buf1/buf2
  __builtin_amdgcn_s_waitcnt(WAIT_LGKM0);
  asm volatile("" ::: "memory");
  __builtin_amdgcn_s_barrier();
  asm volatile("" ::: "memory");
  issue(128, 16384);                                      // (tile0,kt1) -> buf1
  issue(256, 32768);                                      // (tile0,kt2) -> buf2
  // outstanding at loop top: 12 (bufs 0,1,2). No further barriers until epilogue.

  // ---------------- accumulators --------------------------------------------
  // this wave's 32 s-rows: global s-row = nsp*2048 + nt2*128 + wave*32 + l31
  const int brow = (wave * 32 + l31) * 128;
  const int cb0  = ((kc * 2) ^ (l31 & 7)) * 16;
  const int cb1  = cb0 ^ 64;

  f32x16 acc0, acc1;                                      // strip0, strip1
  float rmax0[16], rmax1[16];
  #pragma unroll
  for (int r = 0; r < 16; ++r) { rmax0[r] = -2.0f; rmax1[r] = -2.0f; }

  auto computeK = [&](int kt, int rdo) {
    const unsigned char* Bb = sbuf + rdo;
    int8v b0, b1;
    ((int4*)&b0)[0] = *(const int4*)&Bb[brow + cb0];
    ((int4*)&b0)[1] = *(const int4*)&Bb[brow + (cb0 ^ 16)];
    ((int4*)&b1)[0] = *(const int4*)&Bb[brow + cb1];
    ((int4*)&b1)[1] = *(const int4*)&Bb[brow + (cb1 ^ 16)];
    __builtin_amdgcn_s_setprio(1);
    acc0 = __builtin_amdgcn_mfma_scale_f32_32x32x64_f8f6f4(
        a[0][kt * 2], b0, acc0, 0, 0, 0, 0x7f7f7f7f, 0, 0x7f7f7f7f);
    acc1 = __builtin_amdgcn_mfma_scale_f32_32x32x64_f8f6f4(
        a[1][kt * 2], b0, acc1, 0, 0, 0, 0x7f7f7f7f, 0, 0x7f7f7f7f);
    acc0 = __builtin_amdgcn_mfma_scale_f32_32x32x64_f8f6f4(
        a[0][kt * 2 + 1], b1, acc0, 0, 0, 0, 0x7f7f7f7f, 0, 0x7f7f7f7f);
    acc1 = __builtin_amdgcn_mfma_scale_f32_32x32x64_f8f6f4(
        a[1][kt * 2 + 1], b1, acc1, 0, 0, 0, 0x7f7f7f7f, 0, 0x7f7f7f7f);
    __builtin_amdgcn_s_setprio(0);
  };

  // per-wave step: issue(step+3); wait vmcnt(12); ds_read; 4 MFMA
  #define KSTEP(WAITIMM)                       \
    asm volatile("" ::: "memory");             \
    __builtin_amdgcn_s_waitcnt(WAITIMM);       \
    asm volatile("" ::: "memory");

  #pragma clang loop unroll(disable)
  for (int nt2 = 0; nt2 < 16; ++nt2) {
    const size_t ntb = (size_t)nt2 << 16;                 // 128 rows * 512 B
    const bool more = (nt2 < 15);

    #pragma unroll
    for (int r = 0; r < 16; ++r) { acc0[r] = 0.f; acc1[r] = 0.f; }

    // kt=0 : issue (tile,kt3) -> buf3 ; compute buf0
    issue(ntb + 384, 49152);
    KSTEP(WAIT_VM12);
    computeK(0, 0);

    // kt=1 : issue (tile+1,kt0) -> buf0 ; compute buf1
    if (more) { issue(ntb + 65536, 0); KSTEP(WAIT_VM12); }
    else      { KSTEP(WAIT_VM8); }
    computeK(1, 16384);

    // kt=2 : issue (tile+1,kt1) -> buf1 ; compute buf2
    if (more) { issue(ntb + 65536 + 128, 16384); KSTEP(WAIT_VM12); }
    else      { KSTEP(WAIT_VM4); }
    computeK(2, 32768);

    // kt=3 : issue (tile+1,kt2) -> buf2 ; compute buf3
    if (more) { issue(ntb + 65536 + 256, 32768); KSTEP(WAIT_VM12); }
    else      { KSTEP(WAIT_VM0); }
    computeK(3, 49152);

    #pragma unroll
    for (int r = 0; r < 16; ++r) {
      rmax0[r] = fmaxf(rmax0[r], acc0[r]);
      rmax1[r] = fmaxf(rmax1[r], acc1[r]);
    }
  }
  #undef KSTEP

  // ---------------- epilogue -------------------------------------------------
  // 32x32 C/D: col = lane&31 (s-row in quarter), row = (reg&3)+8*(reg>>2)+4*(lane>>5)
  #pragma unroll
  for (int m = 0; m < 2; ++m) {
    #pragma unroll
    for (int r = 0; r < 16; ++r) {
      float v = m ? rmax1[r] : rmax0[r];
      v = fmaxf(v, __shfl_xor(v, 1, 64));
      v = fmaxf(v, __shfl_xor(v, 2, 64));
      v = fmaxf(v, __shfl_xor(v, 4, 64));
      v = fmaxf(v, __shfl_xor(v, 8, 64));
      v = fmaxf(v, __shfl_xor(v, 16, 64));
      if (l31 == 0)
        maxbuf[m * 32 + (r & 3) + 8 * (r >> 2) + 4 * kc][wave] = v;
    }
  }
  __syncthreads();

  if (tid < 64) {
    float v = fmaxf(fmaxf(maxbuf[tid][0], maxbuf[tid][1]),
                    fmaxf(maxbuf[tid][2], maxbuf[tid][3]));
    unsigned e = __builtin_bit_cast(unsigned, v);
    e = ((int)e >= 0) ? (e | 0x80000000u) : ~e;           // monotone float->uint
    atomicMax(&maxenc[(size_t)b * NQ + (size_t)mt * 64 + tid], e);
  }
}

__global__ void finalize_kernel(const unsigned* __restrict__ maxenc,
                                float* __restrict__ out) {
  int b = blockIdx.x;
  int tid = threadIdx.x;
  float sum = 0.f;
  for (int i = tid; i < NQ; i += 256) {
    unsigned e = maxenc[(size_t)b * NQ + i];
    unsigned u = (e & 0x80000000u) ? (e & 0x7fffffffu) : ~e;
    float v = __builtin_bit_cast(float, u);
    sum += 1.0f - v;
  }
  #pragma unroll
  for (int m = 32; m >= 1; m >>= 1) sum += __shfl_xor(sum, m, 64);
  __shared__ float part[4];
  if ((tid & 63) == 0) part[tid >> 6] = sum;
  __syncthreads();
  if (tid == 0) out[b] = (part[0] + part[1] + part[2] + part[3]) * (1.0f / (float)NQ);
}

// ====================== FALLBACK PATH (round-1, proven, tiny ws) ============
__global__ void norms_kernel(const float* __restrict__ q, const float* __restrict__ s,
                             float* __restrict__ rq, float* __restrict__ rs) {
  int wave = blockIdx.x * 4 + (threadIdx.x >> 6);
  int lane = threadIdx.x & 63;
  const int NQR = NB * NQ, NSR = NB * NS;
  if (wave >= NQR + NSR) return;
  const float4* r4; float* outp;
  if (wave < NQR) { r4 = (const float4*)(q + (size_t)wave * D); outp = rq + wave; }
  else           { r4 = (const float4*)(s + (size_t)(wave - NQR) * D); outp = rs + (wave - NQR); }
  float4 a = r4[lane];
  float4 b = r4[lane + 64];
  float ss = a.x*a.x + a.y*a.y + a.z*a.z + a.w*a.w
           + b.x*b.x + b.y*b.y + b.z*b.z + b.w*b.w;
  #pragma unroll
  for (int m = 32; m >= 1; m >>= 1) ss += __shfl_xor(ss, m, 64);
  if (lane == 0) *outp = 1.0f / fmaxf(sqrtf(ss), 1e-12f);
}

__global__ __launch_bounds__(256, 3) void cosmax_kernel(
    const float* __restrict__ Q, const float* __restrict__ S,
    const float* __restrict__ rq, const float* __restrict__ rs,
    unsigned int* __restrict__ maxenc)
{
  __shared__ short As[BM * BK];
  __shared__ short Bs[BN * BK];
  __shared__ float maxbuf[BM][2];

  const int b  = blockIdx.z, mt = blockIdx.y, nt = blockIdx.x;
  const float* Qb  = Q + ((size_t)b * NQ + mt * BM) * D;
  const float* Sb  = S + ((size_t)b * NS + nt * BN) * D;
  const float* rqb = rq + (size_t)b * NQ + mt * BM;
  const float* rsb = rs + (size_t)b * NS + nt * BN;

  const int tid  = threadIdx.x;
  const int srow = tid >> 2;
  const int kseg = (tid & 3) * 8;
  const float rq0 = rqb[srow], rq1 = rqb[srow + 64];
  const float rs0 = rsb[srow], rs1 = rsb[srow + 64];
  const int wave = tid >> 6, lane = tid & 63;
  const int wm = (wave & 1) * 64, wn = (wave >> 1) * 64;
  const int lm = lane & 15, lk = (lane >> 4) * 8;

  f32x4 acc[4][4];
  #pragma unroll
  for (int i = 0; i < 4; ++i)
    #pragma unroll
    for (int j = 0; j < 4; ++j) acc[i][j] = (f32x4){0.f, 0.f, 0.f, 0.f};

  const float* qrow0 = Qb + (size_t)srow * D + kseg;
  const float* qrow1 = qrow0 + (size_t)64 * D;
  const float* srow0 = Sb + (size_t)srow * D + kseg;
  const float* srow1 = srow0 + (size_t)64 * D;

  float4 qa, qb2, qc, qd, sa, sb2, sc, sd;
  #define LOADK(k0)                                                    \
    qa  = *(const float4*)(qrow0 + (k0));  qb2 = *(const float4*)(qrow0 + (k0) + 4); \
    qc  = *(const float4*)(qrow1 + (k0));  qd  = *(const float4*)(qrow1 + (k0) + 4); \
    sa  = *(const float4*)(srow0 + (k0));  sb2 = *(const float4*)(srow0 + (k0) + 4); \
    sc  = *(const float4*)(srow1 + (k0));  sd  = *(const float4*)(srow1 + (k0) + 4);
  LOADK(0);
  #pragma unroll 4
  for (int kt = 0; kt < D / BK; ++kt) {
    *(short8*)&As[srow        * BK + kseg] = pack8(qa, qb2, rq0);
    *(short8*)&As[(srow + 64) * BK + kseg] = pack8(qc, qd,  rq1);
    *(short8*)&Bs[srow        * BK + kseg] = pack8(sa, sb2, rs0);
    *(short8*)&Bs[(srow + 64) * BK + kseg] = pack8(sc, sd,  rs1);
    __syncthreads();
    if (kt < D / BK - 1) { LOADK((kt + 1) * BK); }
    short8 af[4], bf[4];
    #pragma unroll
    for (int i = 0; i < 4; ++i) af[i] = *(short8*)&As[(wm + i * 16 + lm) * BK + lk];
    #pragma unroll
    for (int j = 0; j < 4; ++j) bf[j] = *(short8*)&Bs[(wn + j * 16 + lm) * BK + lk];
    #pragma unroll
    for (int i = 0; i < 4; ++i)
      #pragma unroll
      for (int j = 0; j < 4; ++j)
        acc[i][j] = __builtin_amdgcn_mfma_f32_16x16x32_bf16(af[i], bf[j], acc[i][j], 0, 0, 0);
    __syncthreads();
  }
  #undef LOADK

  #pragma unroll
  for (int i = 0; i < 4; ++i) {
    #pragma unroll
    for (int r = 0; r < 4; ++r) {
      float v = fmaxf(fmaxf(acc[i][0][r], acc[i][1][r]),
                      fmaxf(acc[i][2][r], acc[i][3][r]));
      v = fmaxf(v, __shfl_xor(v, 1, 64));
      v = fmaxf(v, __shfl_xor(v, 2, 64));
      v = fmaxf(v, __shfl_xor(v, 4, 64));
      v = fmaxf(v, __shfl_xor(v, 8, 64));
      if ((lane & 15) == 0) {
        int row = wm + i * 16 + (lane >> 4) * 4 + r;
        maxbuf[row][wave >> 1] = v;
      }
    }
  }
  __syncthreads();
  if (tid < BM) {
    float v = fmaxf(maxbuf[tid][0], maxbuf[tid][1]);
    unsigned e = __builtin_bit_cast(unsigned, v);
    e = ((int)e >= 0) ? (e | 0x80000000u) : ~e;
    atomicMax(&maxenc[(size_t)b * NQ + mt * BM + tid], e);
  }
}

// ============================================================================
extern "C" void kernel_launch(void* const* d_in, const int* in_sizes, int n_in,
                              void* d_out, int out_size, void* d_ws, size_t ws_size,
                              hipStream_t stream) {
  const float* q = (const float*)d_in[0];   // [8,2048,512]
  const float* s = (const float*)d_in[1];   // [8,4096,512]
  float* out = (float*)d_out;               // [8]

  unsigned* maxenc = (unsigned*)d_ws;                         // 64 KB
  const size_t QOFF = 65536;
  const size_t SOFF = QOFF + (size_t)NB * NQ * D;             // +8 MiB (fp8)
  const size_t NEED = SOFF + (size_t)NB * NS * D;             // +16 MiB (~25.2 MB total)

  if (ws_size >= NEED) {
    unsigned char* qn = (unsigned char*)d_ws + QOFF;
    unsigned char* sn = (unsigned char*)d_ws + SOFF;
    normcvt8_kernel<<<NB * (NQ + NS) / 4, 256, 0, stream>>>(q, s, qn, sn, maxenc);
    cosmax15_kernel<<<512, 256, 0, stream>>>(qn, sn, maxenc);   // barrier-free streams
    finalize_kernel<<<NB, 256, 0, stream>>>(maxenc, out);
  } else {
    float* rq = (float*)((char*)d_ws + 65536);
    float* rs = (float*)((char*)d_ws + 131072);
    hipMemsetAsync(maxenc, 0, (size_t)NB * NQ * sizeof(unsigned), stream);
    norms_kernel<<<NB * (NQ + NS) / 4, 256, 0, stream>>>(q, s, rq, rs);
    dim3 grid(NS / BN, NQ / BM, NB);
    cosmax_kernel<<<grid, 256, 0, stream>>>(q, s, rq, rs, maxenc);
    finalize_kernel<<<NB, 256, 0, stream>>>(maxenc, out);
  }
}